// Round 1
// baseline (804.646 us; speedup 1.0000x reference)
//
#include <hip/hip_runtime.h>

// GraphSAGE fused pipeline, bf16-MFMA v4.
// vs v3: op1+op2 replaced by ONE persistent kernel (pool_fused):
//   - full W (256x256 bf16 = 128 KB) resident in LDS, staged once per block
//     via async global_load_lds; ONE barrier total, then barrier-free.
//   - 256 blocks x 512 threads (8 waves/CU, 1 block/CU); each wave owns
//     whole parents (5 x S=25 f32 parents, + 1 x S=10 bf16 parent for
//     waves 0..1023) -> no inter-wave sync, no W re-staging, no per-k-iter
//     barrier drain.
//   - A streamed global->reg with 2-deep k-tile prefetch + cross-parent
//     prefetch issued before the epilogue (epilogue hides next HBM latency).
// MFMA 16x16x32_bf16 layouts (verified in prior rounds):
//   A-frag: lane holds A[m=lane&15][k=(lane>>4)*8+j]
//   B-frag: lane holds W[n=lane&15][k=(lane>>4)*8+j]   (C = A @ W^T)
//   C/D   : col=lane&15, row=(lane>>4)*4+reg
// W LDS slot (16B) for (nt,kt,quad,lrow) = ((kt*16+nt)*4+quad)*16+lrow;
// staging thread t at iter it writes slot it*512+t (lane-linear, wave-uniform
// base = it*512 + wv*64, as global_load_lds requires).

typedef __bf16 bf16_t;
typedef bf16_t bf16x8 __attribute__((ext_vector_type(8)));
typedef float  f32x4  __attribute__((ext_vector_type(4)));

__device__ inline bf16x8 cvt8(const float4 a, const float4 b) {
  bf16x8 t;
  t[0]=(bf16_t)a.x; t[1]=(bf16_t)a.y; t[2]=(bf16_t)a.z; t[3]=(bf16_t)a.w;
  t[4]=(bf16_t)b.x; t[5]=(bf16_t)b.y; t[6]=(bf16_t)b.z; t[7]=(bf16_t)b.w;
  return t;
}

__global__ __launch_bounds__(256) void cvt_bf16(
    const float* __restrict__ s, bf16_t* __restrict__ d, int n) {
  const int i = (blockIdx.x * 256 + threadIdx.x) * 8;
  if (i < n) {
    const float4 a = *(const float4*)(s + i);
    const float4 b = *(const float4*)(s + i + 4);
    *(bf16x8*)(d + i) = cvt8(a, b);
  }
}

// async global->LDS, 16B per lane; lds dest must be wave-uniform base
__device__ inline void gload_lds16(const bf16_t* g, bf16x8* l) {
  __builtin_amdgcn_global_load_lds(
      (const __attribute__((address_space(1))) unsigned int*)g,
      (__attribute__((address_space(3))) unsigned int*)l, 16, 0, 0);
}

template<typename AT> struct PreA {            // f32 source: cvt on LDS-write
  float4 lo, hi;
  __device__ void fetch(const AT* p) { lo = *(const float4*)p; hi = *(const float4*)(p + 4); }
  __device__ bf16x8 get() const { return cvt8(lo, hi); }
};
template<> struct PreA<bf16_t> {               // bf16 source: raw 16B
  bf16x8 v;
  __device__ void fetch(const bf16_t* p) { v = *(const bf16x8*)p; }
  __device__ bf16x8 get() const { return v; }
};

// ===========================================================================
// pool_fused: persistent, full-W-in-LDS, barrier-free streaming pooled GEMM.
// Phase 1: out1[p] = max_{s<25} relu(A1[p*25+s] @ W^T) * mk1   (A1 f32, 10240 p)
// Phase 2: out2[p] = max_{s<10} relu(A2[p*10+s] @ W^T) * mk0   (A2 bf16, 1024 p)
// ===========================================================================
__global__ __launch_bounds__(512, 2) void pool_fused(
    const float* __restrict__ A1, const bf16_t* __restrict__ A2,
    const bf16_t* __restrict__ W,
    const float* __restrict__ mk1, const float* __restrict__ mk0,
    bf16_t* __restrict__ out1, bf16_t* __restrict__ out2)
{
  __shared__ bf16x8 Wlds[8192];                // 128 KB: full 256x256 bf16 W
  const int tid  = threadIdx.x;
  const int lane = tid & 63, wv = tid >> 6, quad = lane >> 4, lrow = lane & 15;

  // ---- stage full W into LDS (async, 16 B/thread/iter, 16 iters) ----
#pragma unroll
  for (int it = 0; it < 16; ++it) {
    const int s  = it * 512 + tid;
    const int kt = s >> 10, nt = (s >> 6) & 15, q = (s >> 4) & 3, lr = s & 15;
    gload_lds16(W + ((nt * 16 + lr) << 8) + kt * 32 + q * 8,
                &Wlds[it * 512 + wv * 64]);
  }
  __syncthreads();                             // drains async W; ONLY barrier

  const int gw = blockIdx.x * 8 + wv;          // global wave id, 0..2047

  f32x4  acc[2][16];
  float4 blo[2][2], bhi[2][2];                 // [slot][mt] f32 A in flight

  // ---- phase 1: h2 (f32), S=25 -> 2 m-tiles, 5 parents per wave ----
  long p = gw;
  const float* a0 = A1 + (p * 25 + lrow) * 256 + quad * 8;
  const float* a1 = A1 + (p * 25 + (lrow > 8 ? 24 : 16 + lrow)) * 256 + quad * 8;

#define ISS1(sl, kt_) \
    { blo[sl][0] = *(const float4*)(a0 + (kt_) * 32); \
      bhi[sl][0] = *(const float4*)(a0 + (kt_) * 32 + 4); \
      blo[sl][1] = *(const float4*)(a1 + (kt_) * 32); \
      bhi[sl][1] = *(const float4*)(a1 + (kt_) * 32 + 4); }

  ISS1(0, 0); ISS1(1, 1);

#pragma unroll 1
  for (int t = 0; t < 5; ++t) {
    const long pc = p;
    float mk[2][4];                            // mask, issued early, used late
#pragma unroll
    for (int m2 = 0; m2 < 2; ++m2)
#pragma unroll
      for (int r = 0; r < 4; ++r) {
        const int row = m2 * 16 + quad * 4 + r;
        mk[m2][r] = row < 25 ? mk1[pc * 25 + row] : 0.f;
      }
#pragma unroll
    for (int nt = 0; nt < 16; ++nt) {
      acc[0][nt] = (f32x4){0.f, 0.f, 0.f, 0.f};
      acc[1][nt] = (f32x4){0.f, 0.f, 0.f, 0.f};
    }
#pragma unroll
    for (int kt = 0; kt < 8; ++kt) {
      const bf16x8 af0 = cvt8(blo[kt & 1][0], bhi[kt & 1][0]);
      const bf16x8 af1 = cvt8(blo[kt & 1][1], bhi[kt & 1][1]);
      if (kt < 6) ISS1(kt & 1, kt + 2);        // 2-deep k prefetch
#pragma unroll
      for (int nt = 0; nt < 16; ++nt) {
        const bf16x8 bfr = Wlds[((kt * 16 + nt) * 4 + quad) * 16 + lrow];
        acc[0][nt] = __builtin_amdgcn_mfma_f32_16x16x32_bf16(af0, bfr, acc[0][nt], 0, 0, 0);
        acc[1][nt] = __builtin_amdgcn_mfma_f32_16x16x32_bf16(af1, bfr, acc[1][nt], 0, 0, 0);
      }
    }
    p += 2048;
    if (t < 4) {                               // cross-parent prefetch BEFORE
      a0 = A1 + (p * 25 + lrow) * 256 + quad * 8;                 // epilogue:
      a1 = A1 + (p * 25 + (lrow > 8 ? 24 : 16 + lrow)) * 256 + quad * 8;
      ISS1(0, 0); ISS1(1, 1);                  // epilogue hides HBM latency
    }
    // epilogue: relu -> *mask -> max over 25 rows -> out1[pc]
#pragma unroll
    for (int nt = 0; nt < 16; ++nt) {
      float m = 0.f;
#pragma unroll
      for (int m2 = 0; m2 < 2; ++m2) {
        const f32x4 v = acc[m2][nt];
#pragma unroll
        for (int r = 0; r < 4; ++r)
          m = fmaxf(m, fmaxf(v[r], 0.f) * mk[m2][r]);
      }
      m = fmaxf(m, __shfl_xor(m, 16));
      m = fmaxf(m, __shfl_xor(m, 32));
      if (lane < 16) out1[pc * 256 + nt * 16 + lrow] = (bf16_t)m;
    }
  }
#undef ISS1

  // ---- phase 2: h1b (bf16), S=10 -> 1 m-tile, waves 0..1023 ----
  if (gw < 1024) {
    const long p2 = gw;
    const bf16_t* ab = A2 + (p2 * 10 + (lrow > 9 ? 9 : lrow)) * 256 + quad * 8;
    bf16x8 bb0 = *(const bf16x8*)(ab);
    bf16x8 bb1 = *(const bf16x8*)(ab + 32);
    float mk2[4];
#pragma unroll
    for (int r = 0; r < 4; ++r) {
      const int row = quad * 4 + r;
      mk2[r] = row < 10 ? mk0[p2 * 10 + row] : 0.f;
    }
#pragma unroll
    for (int nt = 0; nt < 16; ++nt) acc[0][nt] = (f32x4){0.f, 0.f, 0.f, 0.f};
#pragma unroll
    for (int kt = 0; kt < 8; ++kt) {
      const bf16x8 af = (kt & 1) ? bb1 : bb0;
      if (kt < 6) {
        if (kt & 1) bb1 = *(const bf16x8*)(ab + (kt + 2) * 32);
        else        bb0 = *(const bf16x8*)(ab + (kt + 2) * 32);
      }
#pragma unroll
      for (int nt = 0; nt < 16; ++nt) {
        const bf16x8 bfr = Wlds[((kt * 16 + nt) * 4 + quad) * 16 + lrow];
        acc[0][nt] = __builtin_amdgcn_mfma_f32_16x16x32_bf16(af, bfr, acc[0][nt], 0, 0, 0);
      }
    }
#pragma unroll
    for (int nt = 0; nt < 16; ++nt) {
      float m = 0.f;
      const f32x4 v = acc[0][nt];
#pragma unroll
      for (int r = 0; r < 4; ++r)
        m = fmaxf(m, fmaxf(v[r], 0.f) * mk2[r]);
      m = fmaxf(m, __shfl_xor(m, 16));
      m = fmaxf(m, __shfl_xor(m, 32));
      if (lane < 16) out2[p2 * 256 + nt * 16 + lrow] = (bf16_t)m;
    }
  }
}

// ---- pooled GEMM (kept for op7, K=512): out[p] = max_s relu(A @ W^T)*mask ----
template<int S, int PR, int P, int K, typename AT>
__global__ __launch_bounds__(256) void pool_mfma(
    const AT* __restrict__ A, const bf16_t* __restrict__ W,
    const float* __restrict__ mask, bf16_t* __restrict__ out)
{
  constexpr int ROWS = P * PR;                 // 64
  constexpr int PM   = ROWS / 16;              // 4
  constexpr int MTP  = PR / 16;
  constexpr int T    = K / 32;
  __shared__ bf16x8 Blds[2][1024];             // 32 KB (N=256)
  __shared__ bf16x8 Alds[2][ROWS * 4];         // 8 KB
  __shared__ float  mlds[ROWS];

  const int tid  = threadIdx.x;
  const int lane = tid & 63, wv = tid >> 6, quad = lane >> 4, lrow = lane & 15;
  const long p0  = (long)blockIdx.x * P;

  if (tid < P * S) mlds[(tid / S) * PR + (tid % S)] = mask[p0 * S + tid];

  const bf16_t* wptr[4];
#pragma unroll
  for (int j = 0; j < 4; ++j) {
    const int n = ((tid >> 6) + j * 4) * 16 + (tid & 15);
    wptr[j] = W + (long)n * K + ((tid >> 4) & 3) * 8;
  }
  const int wbase = (tid >> 6) * 64;           // wave-uniform LDS slot base

  const int mr = (tid >> 6) * 16 + (tid & 15);
  const int pp = mr / PR, rr = mr % PR;
  const long grow = (p0 + pp) * (long)S + (rr < S ? rr : S - 1);  // clamp pads
  const AT* aptr = A + grow * (long)K + ((tid >> 4) & 3) * 8;

  f32x4 acc[PM][4];
#pragma unroll
  for (int pm = 0; pm < PM; ++pm)
#pragma unroll
    for (int nl = 0; nl < 4; ++nl) acc[pm][nl] = (f32x4){0.f, 0.f, 0.f, 0.f};

  PreA<AT> a0, apre[2];
  a0.fetch(aptr);
#pragma unroll
  for (int j = 0; j < 4; ++j) gload_lds16(wptr[j], &Blds[0][wbase + j * 256]);
  apre[0].fetch(aptr + 32);
  apre[1].fetch(aptr + 64);
  Alds[0][tid] = a0.get();
  __syncthreads();                             // drains async W too

#pragma unroll
  for (int i = 0; i < T; ++i) {
    const int cur = i & 1, nxt = cur ^ 1;
    if (i + 1 < T) {                           // async W tile i+1 -> other buf
#pragma unroll
      for (int j = 0; j < 4; ++j)
        gload_lds16(wptr[j] + (i + 1) * 32, &Blds[nxt][wbase + j * 256]);
    }
    bf16x8 bfr[4];
#pragma unroll
    for (int nl = 0; nl < 4; ++nl)
      bfr[nl] = Blds[cur][((wv * 4 + nl) * 4 + quad) * 16 + lrow];
#pragma unroll
    for (int pm = 0; pm < PM; ++pm) {
      const bf16x8 afr = Alds[cur][(pm * 4 + quad) * 16 + lrow];
#pragma unroll
      for (int nl = 0; nl < 4; ++nl)
        acc[pm][nl] = __builtin_amdgcn_mfma_f32_16x16x32_bf16(
            afr, bfr[nl], acc[pm][nl], 0, 0, 0);
    }
    if (i + 1 < T) {
      Alds[nxt][tid] = apre[i & 1].get();      // consume tile i+1
      if (i + 3 < T) apre[i & 1].fetch(aptr + (i + 3) * 32);  // fetch tile i+3
      __syncthreads();
    }
  }

  // epilogue: relu -> *mask -> max over S rows per parent
#pragma unroll
  for (int p = 0; p < P; ++p) {
#pragma unroll
    for (int nl = 0; nl < 4; ++nl) {
      float m = 0.f;
#pragma unroll
      for (int mt = 0; mt < MTP; ++mt) {
        const f32x4 v = acc[p * MTP + mt][nl];
#pragma unroll
        for (int reg = 0; reg < 4; ++reg) {
          const int row = mt * 16 + quad * 4 + reg;
          if (row < S)
            m = fmaxf(m, fmaxf(v[reg], 0.f) * mlds[p * PR + row]);
        }
      }
      m = fmaxf(m, __shfl_xor(m, 16));
      m = fmaxf(m, __shfl_xor(m, 32));
      if (lane < 16)
        out[(p0 + p) * 256 + wv * 64 + nl * 16 + lrow] = (bf16_t)m;
    }
  }
}

// ---- plain GEMM: out[r][coff + 0:N] = A[r] @ W^T ; (A,W,coff) by blockIdx.y ----
template<int MT, int N, int K, typename OT>
__global__ __launch_bounds__(256) void plain_mfma(
    const bf16_t* __restrict__ A0, const bf16_t* __restrict__ W0, int c0,
    const bf16_t* __restrict__ A1, const bf16_t* __restrict__ W1, int c1,
    OT* __restrict__ out, int ldc)
{
  constexpr int NTW    = N / 64;
  constexpr int BSLOTS = N * 4;
  constexpr int BPT    = BSLOTS / 256;
  constexpr int ROWS   = MT * 16;
  constexpr int ASLOTS = ROWS * 4;
  constexpr int T      = K / 32;
  __shared__ bf16x8 Blds[2][BSLOTS];
  __shared__ bf16x8 Alds[2][ASLOTS];

  const bf16_t* __restrict__ A = blockIdx.y ? A1 : A0;
  const bf16_t* __restrict__ W = blockIdx.y ? W1 : W0;
  const int coff = blockIdx.y ? c1 : c0;

  const int tid  = threadIdx.x;
  const int lane = tid & 63, wv = tid >> 6, quad = lane >> 4, lrow = lane & 15;
  const long r0  = (long)blockIdx.x * ROWS;

  const bf16_t* wptr[BPT];
#pragma unroll
  for (int j = 0; j < BPT; ++j) {
    const int n = ((tid >> 6) + j * 4) * 16 + (tid & 15);
    wptr[j] = W + (long)n * K + ((tid >> 4) & 3) * 8;
  }
  const int wbase = (tid >> 6) * 64;

  const bool aact = tid < ASLOTS;
  const int  mr   = (tid >> 6) * 16 + (tid & 15);
  const bf16_t* aptr = A + (aact ? (r0 + mr) * (long)K + ((tid >> 4) & 3) * 8 : 0);

  f32x4 acc[MT][NTW];
#pragma unroll
  for (int mt = 0; mt < MT; ++mt)
#pragma unroll
    for (int nl = 0; nl < NTW; ++nl) acc[mt][nl] = (f32x4){0.f, 0.f, 0.f, 0.f};

  PreA<bf16_t> a0p, apre[2];
  if (aact) a0p.fetch(aptr);
#pragma unroll
  for (int j = 0; j < BPT; ++j) gload_lds16(wptr[j], &Blds[0][wbase + j * 256]);
  if (aact) {
    apre[0].fetch(aptr + 32);
    apre[1].fetch(aptr + 64);
    Alds[0][tid] = a0p.get();
  }
  __syncthreads();

#pragma unroll
  for (int i = 0; i < T; ++i) {
    const int cur = i & 1, nxt = cur ^ 1;
    if (i + 1 < T) {
#pragma unroll
      for (int j = 0; j < BPT; ++j)
        gload_lds16(wptr[j] + (i + 1) * 32, &Blds[nxt][wbase + j * 256]);
    }
    bf16x8 bfr[NTW];
#pragma unroll
    for (int nl = 0; nl < NTW; ++nl)
      bfr[nl] = Blds[cur][((wv * NTW + nl) * 4 + quad) * 16 + lrow];
#pragma unroll
    for (int mt = 0; mt < MT; ++mt) {
      const bf16x8 afr = Alds[cur][(mt * 4 + quad) * 16 + lrow];
#pragma unroll
      for (int nl = 0; nl < NTW; ++nl)
        acc[mt][nl] = __builtin_amdgcn_mfma_f32_16x16x32_bf16(
            afr, bfr[nl], acc[mt][nl], 0, 0, 0);
    }
    if (i + 1 < T) {
      if (aact) {
        Alds[nxt][tid] = apre[i & 1].get();
        if (i + 3 < T) apre[i & 1].fetch(aptr + (i + 3) * 32);
      }
      __syncthreads();
    }
  }

#pragma unroll
  for (int mt = 0; mt < MT; ++mt)
#pragma unroll
    for (int nl = 0; nl < NTW; ++nl) {
      const f32x4 v = acc[mt][nl];
      const int col = coff + (wv * NTW + nl) * 16 + lrow;
#pragma unroll
      for (int reg = 0; reg < 4; ++reg) {
        const long row = r0 + mt * 16 + quad * 4 + reg;
        out[row * (long)ldc + col] = (OT)v[reg];
      }
    }
}

extern "C" void kernel_launch(void* const* d_in, const int* in_sizes, int n_in,
                              void* d_out, int out_size, void* d_ws, size_t ws_size,
                              hipStream_t stream) {
  const float* h0f   = (const float*)d_in[0];
  const float* h1f   = (const float*)d_in[1];
  const float* h2    = (const float*)d_in[2];
  const float* mask0 = (const float*)d_in[3];
  const float* mask1 = (const float*)d_in[4];
  const float* Wf[7] = { (const float*)d_in[5], (const float*)d_in[6],
                         (const float*)d_in[7], (const float*)d_in[8],
                         (const float*)d_in[9], (const float*)d_in[10],
                         (const float*)d_in[11] };
  const int   Wn[7]  = { 65536, 65536, 65536, 131072, 131072, 65536, 65536 };
  float* out = (float*)d_out;

  bf16_t* p = (bf16_t*)d_ws;
  bf16_t* Wb[7];
  for (int i = 0; i < 7; ++i) { Wb[i] = p; p += Wn[i]; }
  bf16_t* h0b = p;      p += 262144;               // 1024 x 256
  bf16_t* h1b = p;      p += 2621440;              // 10240 x 256
  bf16_t* pooled1  = p; p += 10240L * 256;
  bf16_t* states1  = p; p += 10240L * 512;
  bf16_t* pooled0  = p; p += 1024L * 256;
  bf16_t* states0  = p; p += 1024L * 512;
  bf16_t* pooled1b = p; p += 1024L * 256;
  bf16_t* states0b = p; p += 1024L * 512;

  const bf16_t *Ws0 = Wb[0], *Wn0 = Wb[1], *Wp0 = Wb[2], *Ws1 = Wb[3],
               *Wn1 = Wb[4], *Wp1 = Wb[5], *Wout = Wb[6];
  const dim3 blk(256);

  // 0. f32 -> bf16 conversions (weights + h0 + h1)
  for (int i = 0; i < 7; ++i)
    hipLaunchKernelGGL(cvt_bf16, dim3(Wn[i] / 2048), blk, 0, stream, Wf[i], Wb[i], Wn[i]);
  hipLaunchKernelGGL(cvt_bf16, dim3(128),  blk, 0, stream, h0f, h0b, 262144);
  hipLaunchKernelGGL(cvt_bf16, dim3(1280), blk, 0, stream, h1f, h1b, 2621440);

  // 1+2 fused (persistent, W-in-LDS):
  //   pooled1 = pool25(relu(h2  @ Wn0^T) * mask1)
  //   pooled0 = pool10(relu(h1b @ Wn0^T) * mask0)
  hipLaunchKernelGGL(pool_fused, dim3(256), dim3(512), 0, stream,
                     h2, h1b, Wn0, mask1, mask0, pooled1, pooled0);
  // 3+4. states1 = [h1 @ Ws0^T | pooled1 @ Wp0^T]
  hipLaunchKernelGGL((plain_mfma<4, 256, 256, bf16_t>), dim3(160, 2), blk, 0, stream,
                     h1b, Ws0, 0, pooled1, Wp0, 256, states1, 512);
  // 5+6. states0 = [h0 @ Ws0^T | pooled0 @ Wp0^T]
  hipLaunchKernelGGL((plain_mfma<1, 256, 256, bf16_t>), dim3(64, 2), blk, 0, stream,
                     h0b, Ws0, 0, pooled0, Wp0, 256, states0, 512);
  // 7. pooled1b = pool10(relu(states1 @ Wn1^T) * mask0), K=512
  hipLaunchKernelGGL((pool_mfma<10, 16, 4, 512, bf16_t>), dim3(256), blk, 0, stream,
                     states1, Wn1, mask0, pooled1b);
  // 8. states0b[:, 0:256] = states0 @ Ws1^T, K=512
  hipLaunchKernelGGL((plain_mfma<1, 256, 512, bf16_t>), dim3(64, 1), blk, 0, stream,
                     states0, Ws1, 0, states0, Ws1, 0, states0b, 512);
  // 9. states0b[:, 256:512] = pooled1b @ Wp1^T, K=256
  hipLaunchKernelGGL((plain_mfma<1, 256, 256, bf16_t>), dim3(64, 1), blk, 0, stream,
                     pooled1b, Wp1, 256, pooled1b, Wp1, 256, states0b, 512);
  // 10. out = states0b @ Wout^T, K=512, N=128, f32 out
  hipLaunchKernelGGL((plain_mfma<1, 128, 512, float>), dim3(64, 1), blk, 0, stream,
                     states0b, Wout, 0, states0b, Wout, 0, out, 128);
}

// Round 2
// 803.536 us; speedup vs baseline: 1.0014x; 1.0014x over previous
//
#include <hip/hip_runtime.h>

// GraphSAGE fused pipeline, bf16-MFMA v5.
// vs v4: ONE change — pool_fused launch bounds (512,2) -> (512,1).
// v4 post-mortem: hipcc treated the 2nd launch_bounds arg as min BLOCKS/CU
// (CUDA semantics): 2 blocks x 8 waves = 16 waves/CU = 4 waves/EU -> 128-VGPR
// cap, but live state is ~190 regs (acc[2][16]=128 + prefetch 32 + addr).
// Result: massive scratch spill (WRITE_SIZE 330 MB vs 5.5 MB legit, FETCH
// 823 MB vs ~290 MB expected), MfmaUtil 4%. The 128 KB LDS already forces
// 1 block/CU, so the cap bought nothing. (512,1) gives a >=256-reg cap under
// either semantics -> no spill.
// MFMA 16x16x32_bf16 layouts (verified in prior rounds):
//   A-frag: lane holds A[m=lane&15][k=(lane>>4)*8+j]
//   B-frag: lane holds W[n=lane&15][k=(lane>>4)*8+j]   (C = A @ W^T)
//   C/D   : col=lane&15, row=(lane>>4)*4+reg
// W LDS slot (16B) for (nt,kt,quad,lrow) = ((kt*16+nt)*4+quad)*16+lrow;
// staging thread t at iter it writes slot it*512+t (lane-linear, wave-uniform
// base = it*512 + wv*64, as global_load_lds requires).

typedef __bf16 bf16_t;
typedef bf16_t bf16x8 __attribute__((ext_vector_type(8)));
typedef float  f32x4  __attribute__((ext_vector_type(4)));

__device__ inline bf16x8 cvt8(const float4 a, const float4 b) {
  bf16x8 t;
  t[0]=(bf16_t)a.x; t[1]=(bf16_t)a.y; t[2]=(bf16_t)a.z; t[3]=(bf16_t)a.w;
  t[4]=(bf16_t)b.x; t[5]=(bf16_t)b.y; t[6]=(bf16_t)b.z; t[7]=(bf16_t)b.w;
  return t;
}

__global__ __launch_bounds__(256) void cvt_bf16(
    const float* __restrict__ s, bf16_t* __restrict__ d, int n) {
  const int i = (blockIdx.x * 256 + threadIdx.x) * 8;
  if (i < n) {
    const float4 a = *(const float4*)(s + i);
    const float4 b = *(const float4*)(s + i + 4);
    *(bf16x8*)(d + i) = cvt8(a, b);
  }
}

// async global->LDS, 16B per lane; lds dest must be wave-uniform base
__device__ inline void gload_lds16(const bf16_t* g, bf16x8* l) {
  __builtin_amdgcn_global_load_lds(
      (const __attribute__((address_space(1))) unsigned int*)g,
      (__attribute__((address_space(3))) unsigned int*)l, 16, 0, 0);
}

template<typename AT> struct PreA {            // f32 source: cvt on LDS-write
  float4 lo, hi;
  __device__ void fetch(const AT* p) { lo = *(const float4*)p; hi = *(const float4*)(p + 4); }
  __device__ bf16x8 get() const { return cvt8(lo, hi); }
};
template<> struct PreA<bf16_t> {               // bf16 source: raw 16B
  bf16x8 v;
  __device__ void fetch(const bf16_t* p) { v = *(const bf16x8*)p; }
  __device__ bf16x8 get() const { return v; }
};

// ===========================================================================
// pool_fused: persistent, full-W-in-LDS, barrier-free streaming pooled GEMM.
// Phase 1: out1[p] = max_{s<25} relu(A1[p*25+s] @ W^T) * mk1   (A1 f32, 10240 p)
// Phase 2: out2[p] = max_{s<10} relu(A2[p*10+s] @ W^T) * mk0   (A2 bf16, 1024 p)
// ===========================================================================
__global__ __launch_bounds__(512, 1) void pool_fused(
    const float* __restrict__ A1, const bf16_t* __restrict__ A2,
    const bf16_t* __restrict__ W,
    const float* __restrict__ mk1, const float* __restrict__ mk0,
    bf16_t* __restrict__ out1, bf16_t* __restrict__ out2)
{
  __shared__ bf16x8 Wlds[8192];                // 128 KB: full 256x256 bf16 W
  const int tid  = threadIdx.x;
  const int lane = tid & 63, wv = tid >> 6, quad = lane >> 4, lrow = lane & 15;

  // ---- stage full W into LDS (async, 16 B/thread/iter, 16 iters) ----
#pragma unroll
  for (int it = 0; it < 16; ++it) {
    const int s  = it * 512 + tid;
    const int kt = s >> 10, nt = (s >> 6) & 15, q = (s >> 4) & 3, lr = s & 15;
    gload_lds16(W + ((nt * 16 + lr) << 8) + kt * 32 + q * 8,
                &Wlds[it * 512 + wv * 64]);
  }
  __syncthreads();                             // drains async W; ONLY barrier

  const int gw = blockIdx.x * 8 + wv;          // global wave id, 0..2047

  f32x4  acc[2][16];
  float4 blo[2][2], bhi[2][2];                 // [slot][mt] f32 A in flight

  // ---- phase 1: h2 (f32), S=25 -> 2 m-tiles, 5 parents per wave ----
  long p = gw;
  const float* a0 = A1 + (p * 25 + lrow) * 256 + quad * 8;
  const float* a1 = A1 + (p * 25 + (lrow > 8 ? 24 : 16 + lrow)) * 256 + quad * 8;

#define ISS1(sl, kt_) \
    { blo[sl][0] = *(const float4*)(a0 + (kt_) * 32); \
      bhi[sl][0] = *(const float4*)(a0 + (kt_) * 32 + 4); \
      blo[sl][1] = *(const float4*)(a1 + (kt_) * 32); \
      bhi[sl][1] = *(const float4*)(a1 + (kt_) * 32 + 4); }

  ISS1(0, 0); ISS1(1, 1);

#pragma unroll 1
  for (int t = 0; t < 5; ++t) {
    const long pc = p;
    float mk[2][4];                            // mask, issued early, used late
#pragma unroll
    for (int m2 = 0; m2 < 2; ++m2)
#pragma unroll
      for (int r = 0; r < 4; ++r) {
        const int row = m2 * 16 + quad * 4 + r;
        mk[m2][r] = row < 25 ? mk1[pc * 25 + row] : 0.f;
      }
#pragma unroll
    for (int nt = 0; nt < 16; ++nt) {
      acc[0][nt] = (f32x4){0.f, 0.f, 0.f, 0.f};
      acc[1][nt] = (f32x4){0.f, 0.f, 0.f, 0.f};
    }
#pragma unroll
    for (int kt = 0; kt < 8; ++kt) {
      const bf16x8 af0 = cvt8(blo[kt & 1][0], bhi[kt & 1][0]);
      const bf16x8 af1 = cvt8(blo[kt & 1][1], bhi[kt & 1][1]);
      if (kt < 6) ISS1(kt & 1, kt + 2);        // 2-deep k prefetch
#pragma unroll
      for (int nt = 0; nt < 16; ++nt) {
        const bf16x8 bfr = Wlds[((kt * 16 + nt) * 4 + quad) * 16 + lrow];
        acc[0][nt] = __builtin_amdgcn_mfma_f32_16x16x32_bf16(af0, bfr, acc[0][nt], 0, 0, 0);
        acc[1][nt] = __builtin_amdgcn_mfma_f32_16x16x32_bf16(af1, bfr, acc[1][nt], 0, 0, 0);
      }
    }
    p += 2048;
    if (t < 4) {                               // cross-parent prefetch BEFORE
      a0 = A1 + (p * 25 + lrow) * 256 + quad * 8;                 // epilogue:
      a1 = A1 + (p * 25 + (lrow > 8 ? 24 : 16 + lrow)) * 256 + quad * 8;
      ISS1(0, 0); ISS1(1, 1);                  // epilogue hides HBM latency
    }
    // epilogue: relu -> *mask -> max over 25 rows -> out1[pc]
#pragma unroll
    for (int nt = 0; nt < 16; ++nt) {
      float m = 0.f;
#pragma unroll
      for (int m2 = 0; m2 < 2; ++m2) {
        const f32x4 v = acc[m2][nt];
#pragma unroll
        for (int r = 0; r < 4; ++r)
          m = fmaxf(m, fmaxf(v[r], 0.f) * mk[m2][r]);
      }
      m = fmaxf(m, __shfl_xor(m, 16));
      m = fmaxf(m, __shfl_xor(m, 32));
      if (lane < 16) out1[pc * 256 + nt * 16 + lrow] = (bf16_t)m;
    }
  }
#undef ISS1

  // ---- phase 2: h1b (bf16), S=10 -> 1 m-tile, waves 0..1023 ----
  if (gw < 1024) {
    const long p2 = gw;
    const bf16_t* ab = A2 + (p2 * 10 + (lrow > 9 ? 9 : lrow)) * 256 + quad * 8;
    bf16x8 bb0 = *(const bf16x8*)(ab);
    bf16x8 bb1 = *(const bf16x8*)(ab + 32);
    float mk2[4];
#pragma unroll
    for (int r = 0; r < 4; ++r) {
      const int row = quad * 4 + r;
      mk2[r] = row < 10 ? mk0[p2 * 10 + row] : 0.f;
    }
#pragma unroll
    for (int nt = 0; nt < 16; ++nt) acc[0][nt] = (f32x4){0.f, 0.f, 0.f, 0.f};
#pragma unroll
    for (int kt = 0; kt < 8; ++kt) {
      const bf16x8 af = (kt & 1) ? bb1 : bb0;
      if (kt < 6) {
        if (kt & 1) bb1 = *(const bf16x8*)(ab + (kt + 2) * 32);
        else        bb0 = *(const bf16x8*)(ab + (kt + 2) * 32);
      }
#pragma unroll
      for (int nt = 0; nt < 16; ++nt) {
        const bf16x8 bfr = Wlds[((kt * 16 + nt) * 4 + quad) * 16 + lrow];
        acc[0][nt] = __builtin_amdgcn_mfma_f32_16x16x32_bf16(af, bfr, acc[0][nt], 0, 0, 0);
      }
    }
#pragma unroll
    for (int nt = 0; nt < 16; ++nt) {
      float m = 0.f;
      const f32x4 v = acc[0][nt];
#pragma unroll
      for (int r = 0; r < 4; ++r)
        m = fmaxf(m, fmaxf(v[r], 0.f) * mk2[r]);
      m = fmaxf(m, __shfl_xor(m, 16));
      m = fmaxf(m, __shfl_xor(m, 32));
      if (lane < 16) out2[p2 * 256 + nt * 16 + lrow] = (bf16_t)m;
    }
  }
}

// ---- pooled GEMM (kept for op7, K=512): out[p] = max_s relu(A @ W^T)*mask ----
template<int S, int PR, int P, int K, typename AT>
__global__ __launch_bounds__(256) void pool_mfma(
    const AT* __restrict__ A, const bf16_t* __restrict__ W,
    const float* __restrict__ mask, bf16_t* __restrict__ out)
{
  constexpr int ROWS = P * PR;                 // 64
  constexpr int PM   = ROWS / 16;              // 4
  constexpr int MTP  = PR / 16;
  constexpr int T    = K / 32;
  __shared__ bf16x8 Blds[2][1024];             // 32 KB (N=256)
  __shared__ bf16x8 Alds[2][ROWS * 4];         // 8 KB
  __shared__ float  mlds[ROWS];

  const int tid  = threadIdx.x;
  const int lane = tid & 63, wv = tid >> 6, quad = lane >> 4, lrow = lane & 15;
  const long p0  = (long)blockIdx.x * P;

  if (tid < P * S) mlds[(tid / S) * PR + (tid % S)] = mask[p0 * S + tid];

  const bf16_t* wptr[4];
#pragma unroll
  for (int j = 0; j < 4; ++j) {
    const int n = ((tid >> 6) + j * 4) * 16 + (tid & 15);
    wptr[j] = W + (long)n * K + ((tid >> 4) & 3) * 8;
  }
  const int wbase = (tid >> 6) * 64;           // wave-uniform LDS slot base

  const int mr = (tid >> 6) * 16 + (tid & 15);
  const int pp = mr / PR, rr = mr % PR;
  const long grow = (p0 + pp) * (long)S + (rr < S ? rr : S - 1);  // clamp pads
  const AT* aptr = A + grow * (long)K + ((tid >> 4) & 3) * 8;

  f32x4 acc[PM][4];
#pragma unroll
  for (int pm = 0; pm < PM; ++pm)
#pragma unroll
    for (int nl = 0; nl < 4; ++nl) acc[pm][nl] = (f32x4){0.f, 0.f, 0.f, 0.f};

  PreA<AT> a0, apre[2];
  a0.fetch(aptr);
#pragma unroll
  for (int j = 0; j < 4; ++j) gload_lds16(wptr[j], &Blds[0][wbase + j * 256]);
  apre[0].fetch(aptr + 32);
  apre[1].fetch(aptr + 64);
  Alds[0][tid] = a0.get();
  __syncthreads();                             // drains async W too

#pragma unroll
  for (int i = 0; i < T; ++i) {
    const int cur = i & 1, nxt = cur ^ 1;
    if (i + 1 < T) {                           // async W tile i+1 -> other buf
#pragma unroll
      for (int j = 0; j < 4; ++j)
        gload_lds16(wptr[j] + (i + 1) * 32, &Blds[nxt][wbase + j * 256]);
    }
    bf16x8 bfr[4];
#pragma unroll
    for (int nl = 0; nl < 4; ++nl)
      bfr[nl] = Blds[cur][((wv * 4 + nl) * 4 + quad) * 16 + lrow];
#pragma unroll
    for (int pm = 0; pm < PM; ++pm) {
      const bf16x8 afr = Alds[cur][(pm * 4 + quad) * 16 + lrow];
#pragma unroll
      for (int nl = 0; nl < 4; ++nl)
        acc[pm][nl] = __builtin_amdgcn_mfma_f32_16x16x32_bf16(
            afr, bfr[nl], acc[pm][nl], 0, 0, 0);
    }
    if (i + 1 < T) {
      Alds[nxt][tid] = apre[i & 1].get();      // consume tile i+1
      if (i + 3 < T) apre[i & 1].fetch(aptr + (i + 3) * 32);  // fetch tile i+3
      __syncthreads();
    }
  }

  // epilogue: relu -> *mask -> max over S rows per parent
#pragma unroll
  for (int p = 0; p < P; ++p) {
#pragma unroll
    for (int nl = 0; nl < 4; ++nl) {
      float m = 0.f;
#pragma unroll
      for (int mt = 0; mt < MTP; ++mt) {
        const f32x4 v = acc[p * MTP + mt][nl];
#pragma unroll
        for (int reg = 0; reg < 4; ++reg) {
          const int row = mt * 16 + quad * 4 + reg;
          if (row < S)
            m = fmaxf(m, fmaxf(v[reg], 0.f) * mlds[p * PR + row]);
        }
      }
      m = fmaxf(m, __shfl_xor(m, 16));
      m = fmaxf(m, __shfl_xor(m, 32));
      if (lane < 16)
        out[(p0 + p) * 256 + wv * 64 + nl * 16 + lrow] = (bf16_t)m;
    }
  }
}

// ---- plain GEMM: out[r][coff + 0:N] = A[r] @ W^T ; (A,W,coff) by blockIdx.y ----
template<int MT, int N, int K, typename OT>
__global__ __launch_bounds__(256) void plain_mfma(
    const bf16_t* __restrict__ A0, const bf16_t* __restrict__ W0, int c0,
    const bf16_t* __restrict__ A1, const bf16_t* __restrict__ W1, int c1,
    OT* __restrict__ out, int ldc)
{
  constexpr int NTW    = N / 64;
  constexpr int BSLOTS = N * 4;
  constexpr int BPT    = BSLOTS / 256;
  constexpr int ROWS   = MT * 16;
  constexpr int ASLOTS = ROWS * 4;
  constexpr int T      = K / 32;
  __shared__ bf16x8 Blds[2][BSLOTS];
  __shared__ bf16x8 Alds[2][ASLOTS];

  const bf16_t* __restrict__ A = blockIdx.y ? A1 : A0;
  const bf16_t* __restrict__ W = blockIdx.y ? W1 : W0;
  const int coff = blockIdx.y ? c1 : c0;

  const int tid  = threadIdx.x;
  const int lane = tid & 63, wv = tid >> 6, quad = lane >> 4, lrow = lane & 15;
  const long r0  = (long)blockIdx.x * ROWS;

  const bf16_t* wptr[BPT];
#pragma unroll
  for (int j = 0; j < BPT; ++j) {
    const int n = ((tid >> 6) + j * 4) * 16 + (tid & 15);
    wptr[j] = W + (long)n * K + ((tid >> 4) & 3) * 8;
  }
  const int wbase = (tid >> 6) * 64;

  const bool aact = tid < ASLOTS;
  const int  mr   = (tid >> 6) * 16 + (tid & 15);
  const bf16_t* aptr = A + (aact ? (r0 + mr) * (long)K + ((tid >> 4) & 3) * 8 : 0);

  f32x4 acc[MT][NTW];
#pragma unroll
  for (int mt = 0; mt < MT; ++mt)
#pragma unroll
    for (int nl = 0; nl < NTW; ++nl) acc[mt][nl] = (f32x4){0.f, 0.f, 0.f, 0.f};

  PreA<bf16_t> a0p, apre[2];
  if (aact) a0p.fetch(aptr);
#pragma unroll
  for (int j = 0; j < BPT; ++j) gload_lds16(wptr[j], &Blds[0][wbase + j * 256]);
  if (aact) {
    apre[0].fetch(aptr + 32);
    apre[1].fetch(aptr + 64);
    Alds[0][tid] = a0p.get();
  }
  __syncthreads();

#pragma unroll
  for (int i = 0; i < T; ++i) {
    const int cur = i & 1, nxt = cur ^ 1;
    if (i + 1 < T) {
#pragma unroll
      for (int j = 0; j < BPT; ++j)
        gload_lds16(wptr[j] + (i + 1) * 32, &Blds[nxt][wbase + j * 256]);
    }
    bf16x8 bfr[NTW];
#pragma unroll
    for (int nl = 0; nl < NTW; ++nl)
      bfr[nl] = Blds[cur][((wv * NTW + nl) * 4 + quad) * 16 + lrow];
#pragma unroll
    for (int mt = 0; mt < MT; ++mt) {
      const bf16x8 afr = Alds[cur][(mt * 4 + quad) * 16 + lrow];
#pragma unroll
      for (int nl = 0; nl < NTW; ++nl)
        acc[mt][nl] = __builtin_amdgcn_mfma_f32_16x16x32_bf16(
            afr, bfr[nl], acc[mt][nl], 0, 0, 0);
    }
    if (i + 1 < T) {
      if (aact) {
        Alds[nxt][tid] = apre[i & 1].get();
        if (i + 3 < T) apre[i & 1].fetch(aptr + (i + 3) * 32);
      }
      __syncthreads();
    }
  }

#pragma unroll
  for (int mt = 0; mt < MT; ++mt)
#pragma unroll
    for (int nl = 0; nl < NTW; ++nl) {
      const f32x4 v = acc[mt][nl];
      const int col = coff + (wv * NTW + nl) * 16 + lrow;
#pragma unroll
      for (int reg = 0; reg < 4; ++reg) {
        const long row = r0 + mt * 16 + quad * 4 + reg;
        out[row * (long)ldc + col] = (OT)v[reg];
      }
    }
}

extern "C" void kernel_launch(void* const* d_in, const int* in_sizes, int n_in,
                              void* d_out, int out_size, void* d_ws, size_t ws_size,
                              hipStream_t stream) {
  const float* h0f   = (const float*)d_in[0];
  const float* h1f   = (const float*)d_in[1];
  const float* h2    = (const float*)d_in[2];
  const float* mask0 = (const float*)d_in[3];
  const float* mask1 = (const float*)d_in[4];
  const float* Wf[7] = { (const float*)d_in[5], (const float*)d_in[6],
                         (const float*)d_in[7], (const float*)d_in[8],
                         (const float*)d_in[9], (const float*)d_in[10],
                         (const float*)d_in[11] };
  const int   Wn[7]  = { 65536, 65536, 65536, 131072, 131072, 65536, 65536 };
  float* out = (float*)d_out;

  bf16_t* p = (bf16_t*)d_ws;
  bf16_t* Wb[7];
  for (int i = 0; i < 7; ++i) { Wb[i] = p; p += Wn[i]; }
  bf16_t* h0b = p;      p += 262144;               // 1024 x 256
  bf16_t* h1b = p;      p += 2621440;              // 10240 x 256
  bf16_t* pooled1  = p; p += 10240L * 256;
  bf16_t* states1  = p; p += 10240L * 512;
  bf16_t* pooled0  = p; p += 1024L * 256;
  bf16_t* states0  = p; p += 1024L * 512;
  bf16_t* pooled1b = p; p += 1024L * 256;
  bf16_t* states0b = p; p += 1024L * 512;

  const bf16_t *Ws0 = Wb[0], *Wn0 = Wb[1], *Wp0 = Wb[2], *Ws1 = Wb[3],
               *Wn1 = Wb[4], *Wp1 = Wb[5], *Wout = Wb[6];
  const dim3 blk(256);

  // 0. f32 -> bf16 conversions (weights + h0 + h1)
  for (int i = 0; i < 7; ++i)
    hipLaunchKernelGGL(cvt_bf16, dim3(Wn[i] / 2048), blk, 0, stream, Wf[i], Wb[i], Wn[i]);
  hipLaunchKernelGGL(cvt_bf16, dim3(128),  blk, 0, stream, h0f, h0b, 262144);
  hipLaunchKernelGGL(cvt_bf16, dim3(1280), blk, 0, stream, h1f, h1b, 2621440);

  // 1+2 fused (persistent, W-in-LDS):
  //   pooled1 = pool25(relu(h2  @ Wn0^T) * mask1)
  //   pooled0 = pool10(relu(h1b @ Wn0^T) * mask0)
  hipLaunchKernelGGL(pool_fused, dim3(256), dim3(512), 0, stream,
                     h2, h1b, Wn0, mask1, mask0, pooled1, pooled0);
  // 3+4. states1 = [h1 @ Ws0^T | pooled1 @ Wp0^T]
  hipLaunchKernelGGL((plain_mfma<4, 256, 256, bf16_t>), dim3(160, 2), blk, 0, stream,
                     h1b, Ws0, 0, pooled1, Wp0, 256, states1, 512);
  // 5+6. states0 = [h0 @ Ws0^T | pooled0 @ Wp0^T]
  hipLaunchKernelGGL((plain_mfma<1, 256, 256, bf16_t>), dim3(64, 2), blk, 0, stream,
                     h0b, Ws0, 0, pooled0, Wp0, 256, states0, 512);
  // 7. pooled1b = pool10(relu(states1 @ Wn1^T) * mask0), K=512
  hipLaunchKernelGGL((pool_mfma<10, 16, 4, 512, bf16_t>), dim3(256), blk, 0, stream,
                     states1, Wn1, mask0, pooled1b);
  // 8. states0b[:, 0:256] = states0 @ Ws1^T, K=512
  hipLaunchKernelGGL((plain_mfma<1, 256, 512, bf16_t>), dim3(64, 1), blk, 0, stream,
                     states0, Ws1, 0, states0, Ws1, 0, states0b, 512);
  // 9. states0b[:, 256:512] = pooled1b @ Wp1^T, K=256
  hipLaunchKernelGGL((plain_mfma<1, 256, 256, bf16_t>), dim3(64, 1), blk, 0, stream,
                     pooled1b, Wp1, 256, pooled1b, Wp1, 256, states0b, 512);
  // 10. out = states0b @ Wout^T, K=512, N=128, f32 out
  hipLaunchKernelGGL((plain_mfma<1, 128, 512, float>), dim3(64, 1), blk, 0, stream,
                     states0b, Wout, 0, states0b, Wout, 0, out, 128);
}

// Round 3
// 641.109 us; speedup vs baseline: 1.2551x; 1.2534x over previous
//
#include <hip/hip_runtime.h>

// GraphSAGE fused pipeline, bf16-MFMA v6.
// vs v5: pool_fused block 512 -> 256 threads (grid stays 256; each wave now
// owns 10 phase-1 parents + 1 phase-2 parent).
// v5 post-mortem: VGPR_Count/dur/counters were IDENTICAL to v4 — the 128-reg
// cap is NOT launch_bounds-driven. An 8-wave (512-thr) workgroup forces
// 2 waves/SIMD co-resident -> hard cap 512/2 = 256 total regs/wave
// (arch+acc, unified file). Compiler split 128 AGPR (acc[2][16]) + 128 arch;
// remaining ~70 arch regs of prefetch/addr state spilled -> 330 MB scratch
// writes + ~530 MB reloads = the whole 434 us. A 4-wave block = 1 wave/SIMD
// -> 512-reg cap; ~200 live regs fit with zero spill. BW still closes at
// 1 wave/SIMD: 2-deep prefetch = 8 KB/wave = 32 KB/CU in flight >> 9.2 KB
// Little's-law need; LDS W-read traffic ~31 TB/s < 69 TB/s ceiling.
// MFMA 16x16x32_bf16 layouts (verified in prior rounds):
//   A-frag: lane holds A[m=lane&15][k=(lane>>4)*8+j]
//   B-frag: lane holds W[n=lane&15][k=(lane>>4)*8+j]   (C = A @ W^T)
//   C/D   : col=lane&15, row=(lane>>4)*4+reg
// W LDS slot (16B) for (nt,kt,quad,lrow) = ((kt*16+nt)*4+quad)*16+lrow;
// staging thread t at iter it writes slot it*NT+t (lane-linear, wave-uniform
// base = it*NT + wv*64, as global_load_lds requires).

typedef __bf16 bf16_t;
typedef bf16_t bf16x8 __attribute__((ext_vector_type(8)));
typedef float  f32x4  __attribute__((ext_vector_type(4)));

__device__ inline bf16x8 cvt8(const float4 a, const float4 b) {
  bf16x8 t;
  t[0]=(bf16_t)a.x; t[1]=(bf16_t)a.y; t[2]=(bf16_t)a.z; t[3]=(bf16_t)a.w;
  t[4]=(bf16_t)b.x; t[5]=(bf16_t)b.y; t[6]=(bf16_t)b.z; t[7]=(bf16_t)b.w;
  return t;
}

__global__ __launch_bounds__(256) void cvt_bf16(
    const float* __restrict__ s, bf16_t* __restrict__ d, int n) {
  const int i = (blockIdx.x * 256 + threadIdx.x) * 8;
  if (i < n) {
    const float4 a = *(const float4*)(s + i);
    const float4 b = *(const float4*)(s + i + 4);
    *(bf16x8*)(d + i) = cvt8(a, b);
  }
}

// async global->LDS, 16B per lane; lds dest must be wave-uniform base
__device__ inline void gload_lds16(const bf16_t* g, bf16x8* l) {
  __builtin_amdgcn_global_load_lds(
      (const __attribute__((address_space(1))) unsigned int*)g,
      (__attribute__((address_space(3))) unsigned int*)l, 16, 0, 0);
}

template<typename AT> struct PreA {            // f32 source: cvt on LDS-write
  float4 lo, hi;
  __device__ void fetch(const AT* p) { lo = *(const float4*)p; hi = *(const float4*)(p + 4); }
  __device__ bf16x8 get() const { return cvt8(lo, hi); }
};
template<> struct PreA<bf16_t> {               // bf16 source: raw 16B
  bf16x8 v;
  __device__ void fetch(const bf16_t* p) { v = *(const bf16x8*)p; }
  __device__ bf16x8 get() const { return v; }
};

// ===========================================================================
// pool_fused: persistent, full-W-in-LDS, barrier-free streaming pooled GEMM.
// 256 blocks x 256 threads (4 waves, 1 wave/SIMD, 512-reg cap, no spill).
// Phase 1: out1[p] = max_{s<25} relu(A1[p*25+s] @ W^T) * mk1   (A1 f32, 10240 p)
//          wave gw handles p = gw + 1024*t, t = 0..9
// Phase 2: out2[p] = max_{s<10} relu(A2[p*10+s] @ W^T) * mk0   (A2 bf16, 1024 p)
// ===========================================================================
__global__ __launch_bounds__(256, 1) void pool_fused(
    const float* __restrict__ A1, const bf16_t* __restrict__ A2,
    const bf16_t* __restrict__ W,
    const float* __restrict__ mk1, const float* __restrict__ mk0,
    bf16_t* __restrict__ out1, bf16_t* __restrict__ out2)
{
  __shared__ bf16x8 Wlds[8192];                // 128 KB: full 256x256 bf16 W
  const int tid  = threadIdx.x;
  const int lane = tid & 63, wv = tid >> 6, quad = lane >> 4, lrow = lane & 15;

  // ---- stage full W into LDS (async, 16 B/thread/iter, 32 iters) ----
#pragma unroll
  for (int it = 0; it < 32; ++it) {
    const int s  = it * 256 + tid;
    const int kt = s >> 10, nt = (s >> 6) & 15, q = (s >> 4) & 3, lr = s & 15;
    gload_lds16(W + ((nt * 16 + lr) << 8) + kt * 32 + q * 8,
                &Wlds[it * 256 + wv * 64]);
  }
  __syncthreads();                             // drains async W; ONLY barrier

  const int gw = blockIdx.x * 4 + wv;          // global wave id, 0..1023

  f32x4  acc[2][16];
  float4 blo[2][2], bhi[2][2];                 // [slot][mt] f32 A in flight

  // ---- phase 1: h2 (f32), S=25 -> 2 m-tiles, 10 parents per wave ----
  long p = gw;
  const float* a0 = A1 + (p * 25 + lrow) * 256 + quad * 8;
  const float* a1 = A1 + (p * 25 + (lrow > 8 ? 24 : 16 + lrow)) * 256 + quad * 8;

#define ISS1(sl, kt_) \
    { blo[sl][0] = *(const float4*)(a0 + (kt_) * 32); \
      bhi[sl][0] = *(const float4*)(a0 + (kt_) * 32 + 4); \
      blo[sl][1] = *(const float4*)(a1 + (kt_) * 32); \
      bhi[sl][1] = *(const float4*)(a1 + (kt_) * 32 + 4); }

  ISS1(0, 0); ISS1(1, 1);

#pragma unroll 1
  for (int t = 0; t < 10; ++t) {
    const long pc = p;
    float mk[2][4];                            // mask, issued early, used late
#pragma unroll
    for (int m2 = 0; m2 < 2; ++m2)
#pragma unroll
      for (int r = 0; r < 4; ++r) {
        const int row = m2 * 16 + quad * 4 + r;
        mk[m2][r] = row < 25 ? mk1[pc * 25 + row] : 0.f;
      }
#pragma unroll
    for (int nt = 0; nt < 16; ++nt) {
      acc[0][nt] = (f32x4){0.f, 0.f, 0.f, 0.f};
      acc[1][nt] = (f32x4){0.f, 0.f, 0.f, 0.f};
    }
#pragma unroll
    for (int kt = 0; kt < 8; ++kt) {
      const bf16x8 af0 = cvt8(blo[kt & 1][0], bhi[kt & 1][0]);
      const bf16x8 af1 = cvt8(blo[kt & 1][1], bhi[kt & 1][1]);
      if (kt < 6) ISS1(kt & 1, kt + 2);        // 2-deep k prefetch
#pragma unroll
      for (int nt = 0; nt < 16; ++nt) {
        const bf16x8 bfr = Wlds[((kt * 16 + nt) * 4 + quad) * 16 + lrow];
        acc[0][nt] = __builtin_amdgcn_mfma_f32_16x16x32_bf16(af0, bfr, acc[0][nt], 0, 0, 0);
        acc[1][nt] = __builtin_amdgcn_mfma_f32_16x16x32_bf16(af1, bfr, acc[1][nt], 0, 0, 0);
      }
    }
    p += 1024;
    if (t < 9) {                               // cross-parent prefetch BEFORE
      a0 = A1 + (p * 25 + lrow) * 256 + quad * 8;                 // epilogue:
      a1 = A1 + (p * 25 + (lrow > 8 ? 24 : 16 + lrow)) * 256 + quad * 8;
      ISS1(0, 0); ISS1(1, 1);                  // epilogue hides HBM latency
    }
    // epilogue: relu -> *mask -> max over 25 rows -> out1[pc]
#pragma unroll
    for (int nt = 0; nt < 16; ++nt) {
      float m = 0.f;
#pragma unroll
      for (int m2 = 0; m2 < 2; ++m2) {
        const f32x4 v = acc[m2][nt];
#pragma unroll
        for (int r = 0; r < 4; ++r)
          m = fmaxf(m, fmaxf(v[r], 0.f) * mk[m2][r]);
      }
      m = fmaxf(m, __shfl_xor(m, 16));
      m = fmaxf(m, __shfl_xor(m, 32));
      if (lane < 16) out1[pc * 256 + nt * 16 + lrow] = (bf16_t)m;
    }
  }
#undef ISS1

  // ---- phase 2: h1b (bf16), S=10 -> 1 m-tile, 1 parent per wave ----
  {
    const long p2 = gw;
    const bf16_t* ab = A2 + (p2 * 10 + (lrow > 9 ? 9 : lrow)) * 256 + quad * 8;
    bf16x8 bb0 = *(const bf16x8*)(ab);
    bf16x8 bb1 = *(const bf16x8*)(ab + 32);
    float mk2[4];
#pragma unroll
    for (int r = 0; r < 4; ++r) {
      const int row = quad * 4 + r;
      mk2[r] = row < 10 ? mk0[p2 * 10 + row] : 0.f;
    }
#pragma unroll
    for (int nt = 0; nt < 16; ++nt) acc[0][nt] = (f32x4){0.f, 0.f, 0.f, 0.f};
#pragma unroll
    for (int kt = 0; kt < 8; ++kt) {
      const bf16x8 af = (kt & 1) ? bb1 : bb0;
      if (kt < 6) {
        if (kt & 1) bb1 = *(const bf16x8*)(ab + (kt + 2) * 32);
        else        bb0 = *(const bf16x8*)(ab + (kt + 2) * 32);
      }
#pragma unroll
      for (int nt = 0; nt < 16; ++nt) {
        const bf16x8 bfr = Wlds[((kt * 16 + nt) * 4 + quad) * 16 + lrow];
        acc[0][nt] = __builtin_amdgcn_mfma_f32_16x16x32_bf16(af, bfr, acc[0][nt], 0, 0, 0);
      }
    }
#pragma unroll
    for (int nt = 0; nt < 16; ++nt) {
      float m = 0.f;
      const f32x4 v = acc[0][nt];
#pragma unroll
      for (int r = 0; r < 4; ++r)
        m = fmaxf(m, fmaxf(v[r], 0.f) * mk2[r]);
      m = fmaxf(m, __shfl_xor(m, 16));
      m = fmaxf(m, __shfl_xor(m, 32));
      if (lane < 16) out2[p2 * 256 + nt * 16 + lrow] = (bf16_t)m;
    }
  }
}

// ---- pooled GEMM (kept for op7, K=512): out[p] = max_s relu(A @ W^T)*mask ----
template<int S, int PR, int P, int K, typename AT>
__global__ __launch_bounds__(256) void pool_mfma(
    const AT* __restrict__ A, const bf16_t* __restrict__ W,
    const float* __restrict__ mask, bf16_t* __restrict__ out)
{
  constexpr int ROWS = P * PR;                 // 64
  constexpr int PM   = ROWS / 16;              // 4
  constexpr int MTP  = PR / 16;
  constexpr int T    = K / 32;
  __shared__ bf16x8 Blds[2][1024];             // 32 KB (N=256)
  __shared__ bf16x8 Alds[2][ROWS * 4];         // 8 KB
  __shared__ float  mlds[ROWS];

  const int tid  = threadIdx.x;
  const int lane = tid & 63, wv = tid >> 6, quad = lane >> 4, lrow = lane & 15;
  const long p0  = (long)blockIdx.x * P;

  if (tid < P * S) mlds[(tid / S) * PR + (tid % S)] = mask[p0 * S + tid];

  const bf16_t* wptr[4];
#pragma unroll
  for (int j = 0; j < 4; ++j) {
    const int n = ((tid >> 6) + j * 4) * 16 + (tid & 15);
    wptr[j] = W + (long)n * K + ((tid >> 4) & 3) * 8;
  }
  const int wbase = (tid >> 6) * 64;           // wave-uniform LDS slot base

  const int mr = (tid >> 6) * 16 + (tid & 15);
  const int pp = mr / PR, rr = mr % PR;
  const long grow = (p0 + pp) * (long)S + (rr < S ? rr : S - 1);  // clamp pads
  const AT* aptr = A + grow * (long)K + ((tid >> 4) & 3) * 8;

  f32x4 acc[PM][4];
#pragma unroll
  for (int pm = 0; pm < PM; ++pm)
#pragma unroll
    for (int nl = 0; nl < 4; ++nl) acc[pm][nl] = (f32x4){0.f, 0.f, 0.f, 0.f};

  PreA<AT> a0, apre[2];
  a0.fetch(aptr);
#pragma unroll
  for (int j = 0; j < 4; ++j) gload_lds16(wptr[j], &Blds[0][wbase + j * 256]);
  apre[0].fetch(aptr + 32);
  apre[1].fetch(aptr + 64);
  Alds[0][tid] = a0.get();
  __syncthreads();                             // drains async W too

#pragma unroll
  for (int i = 0; i < T; ++i) {
    const int cur = i & 1, nxt = cur ^ 1;
    if (i + 1 < T) {                           // async W tile i+1 -> other buf
#pragma unroll
      for (int j = 0; j < 4; ++j)
        gload_lds16(wptr[j] + (i + 1) * 32, &Blds[nxt][wbase + j * 256]);
    }
    bf16x8 bfr[4];
#pragma unroll
    for (int nl = 0; nl < 4; ++nl)
      bfr[nl] = Blds[cur][((wv * 4 + nl) * 4 + quad) * 16 + lrow];
#pragma unroll
    for (int pm = 0; pm < PM; ++pm) {
      const bf16x8 afr = Alds[cur][(pm * 4 + quad) * 16 + lrow];
#pragma unroll
      for (int nl = 0; nl < 4; ++nl)
        acc[pm][nl] = __builtin_amdgcn_mfma_f32_16x16x32_bf16(
            afr, bfr[nl], acc[pm][nl], 0, 0, 0);
    }
    if (i + 1 < T) {
      Alds[nxt][tid] = apre[i & 1].get();      // consume tile i+1
      if (i + 3 < T) apre[i & 1].fetch(aptr + (i + 3) * 32);  // fetch tile i+3
      __syncthreads();
    }
  }

  // epilogue: relu -> *mask -> max over S rows per parent
#pragma unroll
  for (int p = 0; p < P; ++p) {
#pragma unroll
    for (int nl = 0; nl < 4; ++nl) {
      float m = 0.f;
#pragma unroll
      for (int mt = 0; mt < MTP; ++mt) {
        const f32x4 v = acc[p * MTP + mt][nl];
#pragma unroll
        for (int reg = 0; reg < 4; ++reg) {
          const int row = mt * 16 + quad * 4 + reg;
          if (row < S)
            m = fmaxf(m, fmaxf(v[reg], 0.f) * mlds[p * PR + row]);
        }
      }
      m = fmaxf(m, __shfl_xor(m, 16));
      m = fmaxf(m, __shfl_xor(m, 32));
      if (lane < 16)
        out[(p0 + p) * 256 + wv * 64 + nl * 16 + lrow] = (bf16_t)m;
    }
  }
}

// ---- plain GEMM: out[r][coff + 0:N] = A[r] @ W^T ; (A,W,coff) by blockIdx.y ----
template<int MT, int N, int K, typename OT>
__global__ __launch_bounds__(256) void plain_mfma(
    const bf16_t* __restrict__ A0, const bf16_t* __restrict__ W0, int c0,
    const bf16_t* __restrict__ A1, const bf16_t* __restrict__ W1, int c1,
    OT* __restrict__ out, int ldc)
{
  constexpr int NTW    = N / 64;
  constexpr int BSLOTS = N * 4;
  constexpr int BPT    = BSLOTS / 256;
  constexpr int ROWS   = MT * 16;
  constexpr int ASLOTS = ROWS * 4;
  constexpr int T      = K / 32;
  __shared__ bf16x8 Blds[2][BSLOTS];
  __shared__ bf16x8 Alds[2][ASLOTS];

  const bf16_t* __restrict__ A = blockIdx.y ? A1 : A0;
  const bf16_t* __restrict__ W = blockIdx.y ? W1 : W0;
  const int coff = blockIdx.y ? c1 : c0;

  const int tid  = threadIdx.x;
  const int lane = tid & 63, wv = tid >> 6, quad = lane >> 4, lrow = lane & 15;
  const long r0  = (long)blockIdx.x * ROWS;

  const bf16_t* wptr[BPT];
#pragma unroll
  for (int j = 0; j < BPT; ++j) {
    const int n = ((tid >> 6) + j * 4) * 16 + (tid & 15);
    wptr[j] = W + (long)n * K + ((tid >> 4) & 3) * 8;
  }
  const int wbase = (tid >> 6) * 64;

  const bool aact = tid < ASLOTS;
  const int  mr   = (tid >> 6) * 16 + (tid & 15);
  const bf16_t* aptr = A + (aact ? (r0 + mr) * (long)K + ((tid >> 4) & 3) * 8 : 0);

  f32x4 acc[MT][NTW];
#pragma unroll
  for (int mt = 0; mt < MT; ++mt)
#pragma unroll
    for (int nl = 0; nl < NTW; ++nl) acc[mt][nl] = (f32x4){0.f, 0.f, 0.f, 0.f};

  PreA<bf16_t> a0p, apre[2];
  if (aact) a0p.fetch(aptr);
#pragma unroll
  for (int j = 0; j < BPT; ++j) gload_lds16(wptr[j], &Blds[0][wbase + j * 256]);
  if (aact) {
    apre[0].fetch(aptr + 32);
    apre[1].fetch(aptr + 64);
    Alds[0][tid] = a0p.get();
  }
  __syncthreads();

#pragma unroll
  for (int i = 0; i < T; ++i) {
    const int cur = i & 1, nxt = cur ^ 1;
    if (i + 1 < T) {
#pragma unroll
      for (int j = 0; j < BPT; ++j)
        gload_lds16(wptr[j] + (i + 1) * 32, &Blds[nxt][wbase + j * 256]);
    }
    bf16x8 bfr[NTW];
#pragma unroll
    for (int nl = 0; nl < NTW; ++nl)
      bfr[nl] = Blds[cur][((wv * NTW + nl) * 4 + quad) * 16 + lrow];
#pragma unroll
    for (int mt = 0; mt < MT; ++mt) {
      const bf16x8 afr = Alds[cur][(mt * 4 + quad) * 16 + lrow];
#pragma unroll
      for (int nl = 0; nl < NTW; ++nl)
        acc[mt][nl] = __builtin_amdgcn_mfma_f32_16x16x32_bf16(
            afr, bfr[nl], acc[mt][nl], 0, 0, 0);
    }
    if (i + 1 < T) {
      if (aact) {
        Alds[nxt][tid] = apre[i & 1].get();
        if (i + 3 < T) apre[i & 1].fetch(aptr + (i + 3) * 32);
      }
      __syncthreads();
    }
  }

#pragma unroll
  for (int mt = 0; mt < MT; ++mt)
#pragma unroll
    for (int nl = 0; nl < NTW; ++nl) {
      const f32x4 v = acc[mt][nl];
      const int col = coff + (wv * NTW + nl) * 16 + lrow;
#pragma unroll
      for (int reg = 0; reg < 4; ++reg) {
        const long row = r0 + mt * 16 + quad * 4 + reg;
        out[row * (long)ldc + col] = (OT)v[reg];
      }
    }
}

extern "C" void kernel_launch(void* const* d_in, const int* in_sizes, int n_in,
                              void* d_out, int out_size, void* d_ws, size_t ws_size,
                              hipStream_t stream) {
  const float* h0f   = (const float*)d_in[0];
  const float* h1f   = (const float*)d_in[1];
  const float* h2    = (const float*)d_in[2];
  const float* mask0 = (const float*)d_in[3];
  const float* mask1 = (const float*)d_in[4];
  const float* Wf[7] = { (const float*)d_in[5], (const float*)d_in[6],
                         (const float*)d_in[7], (const float*)d_in[8],
                         (const float*)d_in[9], (const float*)d_in[10],
                         (const float*)d_in[11] };
  const int   Wn[7]  = { 65536, 65536, 65536, 131072, 131072, 65536, 65536 };
  float* out = (float*)d_out;

  bf16_t* p = (bf16_t*)d_ws;
  bf16_t* Wb[7];
  for (int i = 0; i < 7; ++i) { Wb[i] = p; p += Wn[i]; }
  bf16_t* h0b = p;      p += 262144;               // 1024 x 256
  bf16_t* h1b = p;      p += 2621440;              // 10240 x 256
  bf16_t* pooled1  = p; p += 10240L * 256;
  bf16_t* states1  = p; p += 10240L * 512;
  bf16_t* pooled0  = p; p += 1024L * 256;
  bf16_t* states0  = p; p += 1024L * 512;
  bf16_t* pooled1b = p; p += 1024L * 256;
  bf16_t* states0b = p; p += 1024L * 512;

  const bf16_t *Ws0 = Wb[0], *Wn0 = Wb[1], *Wp0 = Wb[2], *Ws1 = Wb[3],
               *Wn1 = Wb[4], *Wp1 = Wb[5], *Wout = Wb[6];
  const dim3 blk(256);

  // 0. f32 -> bf16 conversions (weights + h0 + h1)
  for (int i = 0; i < 7; ++i)
    hipLaunchKernelGGL(cvt_bf16, dim3(Wn[i] / 2048), blk, 0, stream, Wf[i], Wb[i], Wn[i]);
  hipLaunchKernelGGL(cvt_bf16, dim3(128),  blk, 0, stream, h0f, h0b, 262144);
  hipLaunchKernelGGL(cvt_bf16, dim3(1280), blk, 0, stream, h1f, h1b, 2621440);

  // 1+2 fused (persistent, W-in-LDS, 4 waves/block):
  //   pooled1 = pool25(relu(h2  @ Wn0^T) * mask1)
  //   pooled0 = pool10(relu(h1b @ Wn0^T) * mask0)
  hipLaunchKernelGGL(pool_fused, dim3(256), dim3(256), 0, stream,
                     h2, h1b, Wn0, mask1, mask0, pooled1, pooled0);
  // 3+4. states1 = [h1 @ Ws0^T | pooled1 @ Wp0^T]
  hipLaunchKernelGGL((plain_mfma<4, 256, 256, bf16_t>), dim3(160, 2), blk, 0, stream,
                     h1b, Ws0, 0, pooled1, Wp0, 256, states1, 512);
  // 5+6. states0 = [h0 @ Ws0^T | pooled0 @ Wp0^T]
  hipLaunchKernelGGL((plain_mfma<1, 256, 256, bf16_t>), dim3(64, 2), blk, 0, stream,
                     h0b, Ws0, 0, pooled0, Wp0, 256, states0, 512);
  // 7. pooled1b = pool10(relu(states1 @ Wn1^T) * mask0), K=512
  hipLaunchKernelGGL((pool_mfma<10, 16, 4, 512, bf16_t>), dim3(256), blk, 0, stream,
                     states1, Wn1, mask0, pooled1b);
  // 8. states0b[:, 0:256] = states0 @ Ws1^T, K=512
  hipLaunchKernelGGL((plain_mfma<1, 256, 512, bf16_t>), dim3(64, 1), blk, 0, stream,
                     states0, Ws1, 0, states0, Ws1, 0, states0b, 512);
  // 9. states0b[:, 256:512] = pooled1b @ Wp1^T, K=256
  hipLaunchKernelGGL((plain_mfma<1, 256, 256, bf16_t>), dim3(64, 1), blk, 0, stream,
                     pooled1b, Wp1, 256, pooled1b, Wp1, 256, states0b, 512);
  // 10. out = states0b @ Wout^T, K=512, N=128, f32 out
  hipLaunchKernelGGL((plain_mfma<1, 128, 512, float>), dim3(64, 1), blk, 0, stream,
                     states0b, Wout, 0, states0b, Wout, 0, out, 128);
}

// Round 5
// 492.776 us; speedup vs baseline: 1.6329x; 1.3010x over previous
//
#include <hip/hip_runtime.h>

// GraphSAGE fused pipeline, bf16-MFMA v7b (identical to v7; R4 was an infra
// failure with no device signal — resubmitting to get the A/B vs v6).
// vs v6: pool_fused phase-1 register-pressure shaping (v6 still spilled:
// 83 MB scratch writes = exactly 32 f32/thread/parent = the blo/bhi A-prefetch
// buffers; excess FETCH 244 MB = ~3x reloads of spilled values -> pipeline
// destroyed, 2.3 TB/s, MfmaUtil 6.6%). Root cause: the 128-ds_read/256-MFMA
// straight-line kt x nt body lets the scheduler balloon W-fragment transients
// past 256 arch regs; the spiller then evicts the long-lived A buffers.
// Fixes: (1) nt loop split into 2 groups of 8 + sched_barrier(0) after each
// (caps bfr transients ~32 regs, stops cross-kt ballooning); (2) mask load
// moved to kt==5 (live range 8 regs x 2 kt iters instead of whole loop);
// (3) A prefetch 2-deep -> 3-deep (48 KB/CU in flight -> Little's law gives
// ~13 TB/s capability at 1 wave/SIMD). Worst-case arch inventory ~246 <= 256.
// MFMA 16x16x32_bf16 layouts (verified in prior rounds):
//   A-frag: lane holds A[m=lane&15][k=(lane>>4)*8+j]
//   B-frag: lane holds W[n=lane&15][k=(lane>>4)*8+j]   (C = A @ W^T)
//   C/D   : col=lane&15, row=(lane>>4)*4+reg
// W LDS slot (16B) for (nt,kt,quad,lrow) = ((kt*16+nt)*4+quad)*16+lrow;
// staging thread t at iter it writes slot it*NT+t (lane-linear, wave-uniform
// base = it*NT + wv*64, as global_load_lds requires).

typedef __bf16 bf16_t;
typedef bf16_t bf16x8 __attribute__((ext_vector_type(8)));
typedef float  f32x4  __attribute__((ext_vector_type(4)));

__device__ inline bf16x8 cvt8(const float4 a, const float4 b) {
  bf16x8 t;
  t[0]=(bf16_t)a.x; t[1]=(bf16_t)a.y; t[2]=(bf16_t)a.z; t[3]=(bf16_t)a.w;
  t[4]=(bf16_t)b.x; t[5]=(bf16_t)b.y; t[6]=(bf16_t)b.z; t[7]=(bf16_t)b.w;
  return t;
}

__global__ __launch_bounds__(256) void cvt_bf16(
    const float* __restrict__ s, bf16_t* __restrict__ d, int n) {
  const int i = (blockIdx.x * 256 + threadIdx.x) * 8;
  if (i < n) {
    const float4 a = *(const float4*)(s + i);
    const float4 b = *(const float4*)(s + i + 4);
    *(bf16x8*)(d + i) = cvt8(a, b);
  }
}

// async global->LDS, 16B per lane; lds dest must be wave-uniform base
__device__ inline void gload_lds16(const bf16_t* g, bf16x8* l) {
  __builtin_amdgcn_global_load_lds(
      (const __attribute__((address_space(1))) unsigned int*)g,
      (__attribute__((address_space(3))) unsigned int*)l, 16, 0, 0);
}

template<typename AT> struct PreA {            // f32 source: cvt on LDS-write
  float4 lo, hi;
  __device__ void fetch(const AT* p) { lo = *(const float4*)p; hi = *(const float4*)(p + 4); }
  __device__ bf16x8 get() const { return cvt8(lo, hi); }
};
template<> struct PreA<bf16_t> {               // bf16 source: raw 16B
  bf16x8 v;
  __device__ void fetch(const bf16_t* p) { v = *(const bf16x8*)p; }
  __device__ bf16x8 get() const { return v; }
};

// ===========================================================================
// pool_fused: persistent, full-W-in-LDS, barrier-free streaming pooled GEMM.
// 256 blocks x 256 threads (4 waves, 1 wave/SIMD, 512-reg unified cap).
// Phase 1: out1[p] = max_{s<25} relu(A1[p*25+s] @ W^T) * mk1   (A1 f32, 10240 p)
//          wave gw handles p = gw + 1024*t, t = 0..9
// Phase 2: out2[p] = max_{s<10} relu(A2[p*10+s] @ W^T) * mk0   (A2 bf16, 1024 p)
// ===========================================================================
__global__ __launch_bounds__(256, 1) void pool_fused(
    const float* __restrict__ A1, const bf16_t* __restrict__ A2,
    const bf16_t* __restrict__ W,
    const float* __restrict__ mk1, const float* __restrict__ mk0,
    bf16_t* __restrict__ out1, bf16_t* __restrict__ out2)
{
  __shared__ bf16x8 Wlds[8192];                // 128 KB: full 256x256 bf16 W
  const int tid  = threadIdx.x;
  const int lane = tid & 63, wv = tid >> 6, quad = lane >> 4, lrow = lane & 15;

  // ---- stage full W into LDS (async, 16 B/thread/iter, 32 iters) ----
#pragma unroll
  for (int it = 0; it < 32; ++it) {
    const int s  = it * 256 + tid;
    const int kt = s >> 10, nt = (s >> 6) & 15, q = (s >> 4) & 3, lr = s & 15;
    gload_lds16(W + ((nt * 16 + lr) << 8) + kt * 32 + q * 8,
                &Wlds[it * 256 + wv * 64]);
  }
  __syncthreads();                             // drains async W; ONLY barrier

  const int gw = blockIdx.x * 4 + wv;          // global wave id, 0..1023

  f32x4  acc[2][16];
  float4 blo[3][2], bhi[3][2];                 // [slot][mt] f32 A, 3-deep

  // ---- phase 1: h2 (f32), S=25 -> 2 m-tiles, 10 parents per wave ----
  long p = gw;
  const float* a0 = A1 + (p * 25 + lrow) * 256 + quad * 8;
  const float* a1 = A1 + (p * 25 + (lrow > 8 ? 24 : 16 + lrow)) * 256 + quad * 8;

#define ISS1(sl, kt_) \
    { blo[sl][0] = *(const float4*)(a0 + (kt_) * 32); \
      bhi[sl][0] = *(const float4*)(a0 + (kt_) * 32 + 4); \
      blo[sl][1] = *(const float4*)(a1 + (kt_) * 32); \
      bhi[sl][1] = *(const float4*)(a1 + (kt_) * 32 + 4); }

  ISS1(0, 0); ISS1(1, 1); ISS1(2, 2);

#pragma unroll 1
  for (int t = 0; t < 10; ++t) {
    const long pc = p;
    float mk[2][4];                            // loaded at kt==5 (short range)
#pragma unroll
    for (int nt = 0; nt < 16; ++nt) {
      acc[0][nt] = (f32x4){0.f, 0.f, 0.f, 0.f};
      acc[1][nt] = (f32x4){0.f, 0.f, 0.f, 0.f};
    }
#pragma unroll
    for (int kt = 0; kt < 8; ++kt) {
      const int sl = kt % 3;
      const bf16x8 af0 = cvt8(blo[sl][0], bhi[sl][0]);
      const bf16x8 af1 = cvt8(blo[sl][1], bhi[sl][1]);
      if (kt < 5) ISS1(sl, kt + 3);            // 3-deep k prefetch
      if (kt == 5) {                           // mask for current parent:
#pragma unroll                                 // issued 2 kt iters before use
        for (int m2 = 0; m2 < 2; ++m2)
#pragma unroll
          for (int r = 0; r < 4; ++r) {
            const int row = m2 * 16 + quad * 4 + r;
            mk[m2][r] = row < 25 ? mk1[pc * 25 + row] : 0.f;
          }
      }
#pragma unroll
      for (int ntg = 0; ntg < 2; ++ntg) {      // 2 groups of 8: caps hoisted
#pragma unroll                                 // bfr transients at ~32 regs
        for (int nl = 0; nl < 8; ++nl) {
          const int nt = ntg * 8 + nl;
          const bf16x8 bfr = Wlds[((kt * 16 + nt) * 4 + quad) * 16 + lrow];
          acc[0][nt] = __builtin_amdgcn_mfma_f32_16x16x32_bf16(af0, bfr, acc[0][nt], 0, 0, 0);
          acc[1][nt] = __builtin_amdgcn_mfma_f32_16x16x32_bf16(af1, bfr, acc[1][nt], 0, 0, 0);
        }
        __builtin_amdgcn_sched_barrier(0);     // stop cross-group ballooning
      }
    }
    p += 1024;
    if (t < 9) {                               // cross-parent prefetch BEFORE
      a0 = A1 + (p * 25 + lrow) * 256 + quad * 8;                 // epilogue:
      a1 = A1 + (p * 25 + (lrow > 8 ? 24 : 16 + lrow)) * 256 + quad * 8;
      ISS1(0, 0); ISS1(1, 1); ISS1(2, 2);      // epilogue hides HBM latency
    }
    // epilogue: relu -> *mask -> max over 25 rows -> out1[pc]
#pragma unroll
    for (int nt = 0; nt < 16; ++nt) {
      float m = 0.f;
#pragma unroll
      for (int m2 = 0; m2 < 2; ++m2) {
        const f32x4 v = acc[m2][nt];
#pragma unroll
        for (int r = 0; r < 4; ++r)
          m = fmaxf(m, fmaxf(v[r], 0.f) * mk[m2][r]);
      }
      m = fmaxf(m, __shfl_xor(m, 16));
      m = fmaxf(m, __shfl_xor(m, 32));
      if (lane < 16) out1[pc * 256 + nt * 16 + lrow] = (bf16_t)m;
    }
  }
#undef ISS1

  // ---- phase 2: h1b (bf16), S=10 -> 1 m-tile, 1 parent per wave ----
  {
    const long p2 = gw;
    const bf16_t* ab = A2 + (p2 * 10 + (lrow > 9 ? 9 : lrow)) * 256 + quad * 8;
    bf16x8 bb0 = *(const bf16x8*)(ab);
    bf16x8 bb1 = *(const bf16x8*)(ab + 32);
    float mk2[4];
#pragma unroll
    for (int r = 0; r < 4; ++r) {
      const int row = quad * 4 + r;
      mk2[r] = row < 10 ? mk0[p2 * 10 + row] : 0.f;
    }
#pragma unroll
    for (int nt = 0; nt < 16; ++nt) acc[0][nt] = (f32x4){0.f, 0.f, 0.f, 0.f};
#pragma unroll
    for (int kt = 0; kt < 8; ++kt) {
      const bf16x8 af = (kt & 1) ? bb1 : bb0;
      if (kt < 6) {
        if (kt & 1) bb1 = *(const bf16x8*)(ab + (kt + 2) * 32);
        else        bb0 = *(const bf16x8*)(ab + (kt + 2) * 32);
      }
#pragma unroll
      for (int nt = 0; nt < 16; ++nt) {
        const bf16x8 bfr = Wlds[((kt * 16 + nt) * 4 + quad) * 16 + lrow];
        acc[0][nt] = __builtin_amdgcn_mfma_f32_16x16x32_bf16(af, bfr, acc[0][nt], 0, 0, 0);
      }
    }
#pragma unroll
    for (int nt = 0; nt < 16; ++nt) {
      float m = 0.f;
      const f32x4 v = acc[0][nt];
#pragma unroll
      for (int r = 0; r < 4; ++r)
        m = fmaxf(m, fmaxf(v[r], 0.f) * mk2[r]);
      m = fmaxf(m, __shfl_xor(m, 16));
      m = fmaxf(m, __shfl_xor(m, 32));
      if (lane < 16) out2[p2 * 256 + nt * 16 + lrow] = (bf16_t)m;
    }
  }
}

// ---- pooled GEMM (kept for op7, K=512): out[p] = max_s relu(A @ W^T)*mask ----
template<int S, int PR, int P, int K, typename AT>
__global__ __launch_bounds__(256) void pool_mfma(
    const AT* __restrict__ A, const bf16_t* __restrict__ W,
    const float* __restrict__ mask, bf16_t* __restrict__ out)
{
  constexpr int ROWS = P * PR;                 // 64
  constexpr int PM   = ROWS / 16;              // 4
  constexpr int MTP  = PR / 16;
  constexpr int T    = K / 32;
  __shared__ bf16x8 Blds[2][1024];             // 32 KB (N=256)
  __shared__ bf16x8 Alds[2][ROWS * 4];         // 8 KB
  __shared__ float  mlds[ROWS];

  const int tid  = threadIdx.x;
  const int lane = tid & 63, wv = tid >> 6, quad = lane >> 4, lrow = lane & 15;
  const long p0  = (long)blockIdx.x * P;

  if (tid < P * S) mlds[(tid / S) * PR + (tid % S)] = mask[p0 * S + tid];

  const bf16_t* wptr[4];
#pragma unroll
  for (int j = 0; j < 4; ++j) {
    const int n = ((tid >> 6) + j * 4) * 16 + (tid & 15);
    wptr[j] = W + (long)n * K + ((tid >> 4) & 3) * 8;
  }
  const int wbase = (tid >> 6) * 64;           // wave-uniform LDS slot base

  const int mr = (tid >> 6) * 16 + (tid & 15);
  const int pp = mr / PR, rr = mr % PR;
  const long grow = (p0 + pp) * (long)S + (rr < S ? rr : S - 1);  // clamp pads
  const AT* aptr = A + grow * (long)K + ((tid >> 4) & 3) * 8;

  f32x4 acc[PM][4];
#pragma unroll
  for (int pm = 0; pm < PM; ++pm)
#pragma unroll
    for (int nl = 0; nl < 4; ++nl) acc[pm][nl] = (f32x4){0.f, 0.f, 0.f, 0.f};

  PreA<AT> a0, apre[2];
  a0.fetch(aptr);
#pragma unroll
  for (int j = 0; j < 4; ++j) gload_lds16(wptr[j], &Blds[0][wbase + j * 256]);
  apre[0].fetch(aptr + 32);
  apre[1].fetch(aptr + 64);
  Alds[0][tid] = a0.get();
  __syncthreads();                             // drains async W too

#pragma unroll
  for (int i = 0; i < T; ++i) {
    const int cur = i & 1, nxt = cur ^ 1;
    if (i + 1 < T) {                           // async W tile i+1 -> other buf
#pragma unroll
      for (int j = 0; j < 4; ++j)
        gload_lds16(wptr[j] + (i + 1) * 32, &Blds[nxt][wbase + j * 256]);
    }
    bf16x8 bfr[4];
#pragma unroll
    for (int nl = 0; nl < 4; ++nl)
      bfr[nl] = Blds[cur][((wv * 4 + nl) * 4 + quad) * 16 + lrow];
#pragma unroll
    for (int pm = 0; pm < PM; ++pm) {
      const bf16x8 afr = Alds[cur][(pm * 4 + quad) * 16 + lrow];
#pragma unroll
      for (int nl = 0; nl < 4; ++nl)
        acc[pm][nl] = __builtin_amdgcn_mfma_f32_16x16x32_bf16(
            afr, bfr[nl], acc[pm][nl], 0, 0, 0);
    }
    if (i + 1 < T) {
      Alds[nxt][tid] = apre[i & 1].get();      // consume tile i+1
      if (i + 3 < T) apre[i & 1].fetch(aptr + (i + 3) * 32);  // fetch tile i+3
      __syncthreads();
    }
  }

  // epilogue: relu -> *mask -> max over S rows per parent
#pragma unroll
  for (int p = 0; p < P; ++p) {
#pragma unroll
    for (int nl = 0; nl < 4; ++nl) {
      float m = 0.f;
#pragma unroll
      for (int mt = 0; mt < MTP; ++mt) {
        const f32x4 v = acc[p * MTP + mt][nl];
#pragma unroll
        for (int reg = 0; reg < 4; ++reg) {
          const int row = mt * 16 + quad * 4 + reg;
          if (row < S)
            m = fmaxf(m, fmaxf(v[reg], 0.f) * mlds[p * PR + row]);
        }
      }
      m = fmaxf(m, __shfl_xor(m, 16));
      m = fmaxf(m, __shfl_xor(m, 32));
      if (lane < 16)
        out[(p0 + p) * 256 + wv * 64 + nl * 16 + lrow] = (bf16_t)m;
    }
  }
}

// ---- plain GEMM: out[r][coff + 0:N] = A[r] @ W^T ; (A,W,coff) by blockIdx.y ----
template<int MT, int N, int K, typename OT>
__global__ __launch_bounds__(256) void plain_mfma(
    const bf16_t* __restrict__ A0, const bf16_t* __restrict__ W0, int c0,
    const bf16_t* __restrict__ A1, const bf16_t* __restrict__ W1, int c1,
    OT* __restrict__ out, int ldc)
{
  constexpr int NTW    = N / 64;
  constexpr int BSLOTS = N * 4;
  constexpr int BPT    = BSLOTS / 256;
  constexpr int ROWS   = MT * 16;
  constexpr int ASLOTS = ROWS * 4;
  constexpr int T      = K / 32;
  __shared__ bf16x8 Blds[2][BSLOTS];
  __shared__ bf16x8 Alds[2][ASLOTS];

  const bf16_t* __restrict__ A = blockIdx.y ? A1 : A0;
  const bf16_t* __restrict__ W = blockIdx.y ? W1 : W0;
  const int coff = blockIdx.y ? c1 : c0;

  const int tid  = threadIdx.x;
  const int lane = tid & 63, wv = tid >> 6, quad = lane >> 4, lrow = lane & 15;
  const long r0  = (long)blockIdx.x * ROWS;

  const bf16_t* wptr[BPT];
#pragma unroll
  for (int j = 0; j < BPT; ++j) {
    const int n = ((tid >> 6) + j * 4) * 16 + (tid & 15);
    wptr[j] = W + (long)n * K + ((tid >> 4) & 3) * 8;
  }
  const int wbase = (tid >> 6) * 64;

  const bool aact = tid < ASLOTS;
  const int  mr   = (tid >> 6) * 16 + (tid & 15);
  const bf16_t* aptr = A + (aact ? (r0 + mr) * (long)K + ((tid >> 4) & 3) * 8 : 0);

  f32x4 acc[MT][NTW];
#pragma unroll
  for (int mt = 0; mt < MT; ++mt)
#pragma unroll
    for (int nl = 0; nl < NTW; ++nl) acc[mt][nl] = (f32x4){0.f, 0.f, 0.f, 0.f};

  PreA<bf16_t> a0p, apre[2];
  if (aact) a0p.fetch(aptr);
#pragma unroll
  for (int j = 0; j < BPT; ++j) gload_lds16(wptr[j], &Blds[0][wbase + j * 256]);
  if (aact) {
    apre[0].fetch(aptr + 32);
    apre[1].fetch(aptr + 64);
    Alds[0][tid] = a0p.get();
  }
  __syncthreads();

#pragma unroll
  for (int i = 0; i < T; ++i) {
    const int cur = i & 1, nxt = cur ^ 1;
    if (i + 1 < T) {
#pragma unroll
      for (int j = 0; j < BPT; ++j)
        gload_lds16(wptr[j] + (i + 1) * 32, &Blds[nxt][wbase + j * 256]);
    }
    bf16x8 bfr[NTW];
#pragma unroll
    for (int nl = 0; nl < NTW; ++nl)
      bfr[nl] = Blds[cur][((wv * NTW + nl) * 4 + quad) * 16 + lrow];
#pragma unroll
    for (int mt = 0; mt < MT; ++mt) {
      const bf16x8 afr = Alds[cur][(mt * 4 + quad) * 16 + lrow];
#pragma unroll
      for (int nl = 0; nl < NTW; ++nl)
        acc[mt][nl] = __builtin_amdgcn_mfma_f32_16x16x32_bf16(
            afr, bfr[nl], acc[mt][nl], 0, 0, 0);
    }
    if (i + 1 < T) {
      if (aact) {
        Alds[nxt][tid] = apre[i & 1].get();
        if (i + 3 < T) apre[i & 1].fetch(aptr + (i + 3) * 32);
      }
      __syncthreads();
    }
  }

#pragma unroll
  for (int mt = 0; mt < MT; ++mt)
#pragma unroll
    for (int nl = 0; nl < NTW; ++nl) {
      const f32x4 v = acc[mt][nl];
      const int col = coff + (wv * NTW + nl) * 16 + lrow;
#pragma unroll
      for (int reg = 0; reg < 4; ++reg) {
        const long row = r0 + mt * 16 + quad * 4 + reg;
        out[row * (long)ldc + col] = (OT)v[reg];
      }
    }
}

extern "C" void kernel_launch(void* const* d_in, const int* in_sizes, int n_in,
                              void* d_out, int out_size, void* d_ws, size_t ws_size,
                              hipStream_t stream) {
  const float* h0f   = (const float*)d_in[0];
  const float* h1f   = (const float*)d_in[1];
  const float* h2    = (const float*)d_in[2];
  const float* mask0 = (const float*)d_in[3];
  const float* mask1 = (const float*)d_in[4];
  const float* Wf[7] = { (const float*)d_in[5], (const float*)d_in[6],
                         (const float*)d_in[7], (const float*)d_in[8],
                         (const float*)d_in[9], (const float*)d_in[10],
                         (const float*)d_in[11] };
  const int   Wn[7]  = { 65536, 65536, 65536, 131072, 131072, 65536, 65536 };
  float* out = (float*)d_out;

  bf16_t* p = (bf16_t*)d_ws;
  bf16_t* Wb[7];
  for (int i = 0; i < 7; ++i) { Wb[i] = p; p += Wn[i]; }
  bf16_t* h0b = p;      p += 262144;               // 1024 x 256
  bf16_t* h1b = p;      p += 2621440;              // 10240 x 256
  bf16_t* pooled1  = p; p += 10240L * 256;
  bf16_t* states1  = p; p += 10240L * 512;
  bf16_t* pooled0  = p; p += 1024L * 256;
  bf16_t* states0  = p; p += 1024L * 512;
  bf16_t* pooled1b = p; p += 1024L * 256;
  bf16_t* states0b = p; p += 1024L * 512;

  const bf16_t *Ws0 = Wb[0], *Wn0 = Wb[1], *Wp0 = Wb[2], *Ws1 = Wb[3],
               *Wn1 = Wb[4], *Wp1 = Wb[5], *Wout = Wb[6];
  const dim3 blk(256);

  // 0. f32 -> bf16 conversions (weights + h0 + h1)
  for (int i = 0; i < 7; ++i)
    hipLaunchKernelGGL(cvt_bf16, dim3(Wn[i] / 2048), blk, 0, stream, Wf[i], Wb[i], Wn[i]);
  hipLaunchKernelGGL(cvt_bf16, dim3(128),  blk, 0, stream, h0f, h0b, 262144);
  hipLaunchKernelGGL(cvt_bf16, dim3(1280), blk, 0, stream, h1f, h1b, 2621440);

  // 1+2 fused (persistent, W-in-LDS, 4 waves/block):
  //   pooled1 = pool25(relu(h2  @ Wn0^T) * mask1)
  //   pooled0 = pool10(relu(h1b @ Wn0^T) * mask0)
  hipLaunchKernelGGL(pool_fused, dim3(256), dim3(256), 0, stream,
                     h2, h1b, Wn0, mask1, mask0, pooled1, pooled0);
  // 3+4. states1 = [h1 @ Ws0^T | pooled1 @ Wp0^T]
  hipLaunchKernelGGL((plain_mfma<4, 256, 256, bf16_t>), dim3(160, 2), blk, 0, stream,
                     h1b, Ws0, 0, pooled1, Wp0, 256, states1, 512);
  // 5+6. states0 = [h0 @ Ws0^T | pooled0 @ Wp0^T]
  hipLaunchKernelGGL((plain_mfma<1, 256, 256, bf16_t>), dim3(64, 2), blk, 0, stream,
                     h0b, Ws0, 0, pooled0, Wp0, 256, states0, 512);
  // 7. pooled1b = pool10(relu(states1 @ Wn1^T) * mask0), K=512
  hipLaunchKernelGGL((pool_mfma<10, 16, 4, 512, bf16_t>), dim3(256), blk, 0, stream,
                     states1, Wn1, mask0, pooled1b);
  // 8. states0b[:, 0:256] = states0 @ Ws1^T, K=512
  hipLaunchKernelGGL((plain_mfma<1, 256, 512, bf16_t>), dim3(64, 1), blk, 0, stream,
                     states0, Ws1, 0, states0, Ws1, 0, states0b, 512);
  // 9. states0b[:, 256:512] = pooled1b @ Wp1^T, K=256
  hipLaunchKernelGGL((plain_mfma<1, 256, 256, bf16_t>), dim3(64, 1), blk, 0, stream,
                     pooled1b, Wp1, 256, pooled1b, Wp1, 256, states0b, 512);
  // 10. out = states0b @ Wout^T, K=512, N=128, f32 out
  hipLaunchKernelGGL((plain_mfma<1, 128, 512, float>), dim3(64, 1), blk, 0, stream,
                     states0b, Wout, 0, states0b, Wout, 0, out, 128);
}